// Round 5
// baseline (2288.960 us; speedup 1.0000x reference)
//
#include <hip/hip_runtime.h>
#include <cstdio>
#include <cstdint>

typedef __bf16 bf16_t;
typedef __bf16 bf16x8 __attribute__((ext_vector_type(8)));
typedef __bf16 bf16x4 __attribute__((ext_vector_type(4)));
typedef float  f32x4  __attribute__((ext_vector_type(4)));

// problem dims
#define B_ROWS 8192
#define GEN    5000
#define GENP   5120   // padded: K of gemm1, N of merger (mult of 320 and 64)
#define H1     4128
#define H1P    4480   // mult of 320 (gemm256 N), 128 (gemm_bt N), 64 (K)
#define H2     2064
#define H2P    2176   // mult of 128
#define LT     1032
#define LTP    1152   // mult of 64

// ---------------- async global->LDS helper ----------------
__device__ __forceinline__ void load_lds16(const bf16_t* g, bf16_t* l) {
  __builtin_amdgcn_global_load_lds((__attribute__((address_space(1))) void*)g,
                                   (__attribute__((address_space(3))) void*)l,
                                   16, 0, 0);
}

__device__ __forceinline__ int xcd_swizzle(int wg, int nwg) {
  const int q = nwg >> 3, r8 = nwg & 7;
  const int xcd = wg & 7, sidx = wg >> 3;
  return (xcd < r8 ? xcd * (q + 1) : r8 * (q + 1) + (xcd - r8) * q) + sidx;
}

// =======================================================================
// 256x320 8-wave 8-phase GEMM, counted vmcnt (T3+T4+T5), BK=64.
// Waves 2M x 4N -> wave tile 128x80 (acc 8x5). LDS 144 KiB:
//   As[2][256*64] + Bs[2][320*64], granule-XOR swizzle (source-side).
// 2 K-tiles/iter (T even -> buf0, T+1 -> buf1), 9 loads per K-tile (A4+B5):
//   P1/P2: A[T+1]->buf1 (2+2)   P3/P4: B[T+2]->buf0 (2+3)
//   P5/P6: A[T+2]->buf0 (2+2)   P7/P8: B[T+3]->buf1 (2+3)
// vmcnt(5) only at P4/P8. Ledger (steady state, 5 outstanding entering iter
// = B[T+1]): P4-end has 14 in flight; vmcnt(5) completes B[T+1](5)+A[T+1](4)
// = exactly what P5-P8 read; leaves B[T+2](5). Symmetric at P8.
// Buffer-free: A-buf1 free after prev-P7 (ahi of T-1), B-buf0 free after P2
// (b of T), A-buf0 free after P3 (ahi of T), B-buf1 free after P6 (b of T+1).
// MODE 0: bf16 C (ld Npad) + per-column sum/sumsq atomics.
// MODE 1: f32 C (ld Nvalid, col-bounded).
// =======================================================================
template<int MODE>
__global__ __launch_bounds__(512, 2)
void gemm256(const bf16_t* __restrict__ A, const bf16_t* __restrict__ Bm,
             int K, bf16_t* __restrict__ Cb, int Npad,
             float* __restrict__ sum, float* __restrict__ sq,
             float* __restrict__ Cf, int Nvalid)
{
  __shared__ bf16_t As[2][256 * 64];
  __shared__ bf16_t Bs[2][320 * 64];
  const int tid  = threadIdx.x;
  const int wave = tid >> 6;
  const int lane = tid & 63;

  int wg = xcd_swizzle((int)blockIdx.x + (int)blockIdx.y * gridDim.x,
                       gridDim.x * gridDim.y);
  const int brow = (wg / gridDim.x) * 256;
  const int bcol = (wg % gridDim.x) * 320;

  const int wm = wave >> 2;      // 0..1 -> 128-row half
  const int wn = wave & 3;       // 0..3 -> 80-col slice

  // staging: 8 threads per 64-elem row, 16B granule, XOR-swizzled source
  const int rr = tid >> 3;                        // 0..63
  const int cc = (((tid & 7) ^ (rr & 7)) << 3);
  const bf16_t* ga = A  + (size_t)(brow + rr) * K + cc;
  const bf16_t* gb = Bm + (size_t)(bcol + rr) * K + cc;

  auto stA = [&](int d, int i, long ko) {
    load_lds16(ga + (size_t)(i * 64) * K + ko, &As[d][(i * 64 + wave * 8) * 64]);
  };
  auto stB = [&](int d, int i, long ko) {
    load_lds16(gb + (size_t)(i * 64) * K + ko, &Bs[d][(i * 64 + wave * 8) * 64]);
  };

  f32x4 acc[8][5] = {};
  bf16x8 alo[4][2], ahi[4][2], b01[2][2], b234[3][2];

  const int lr  = lane & 15;
  const int hi  = lane >> 4;
  const int rsw = lr & 7;
  const int arb = wm * 128 + lr;  // A row base (+ MB*64 + mf*16)
  const int bcb = wn * 80 + lr;   // B col base (+ nf*16); 80,16 mult of 8 -> row&7==rsw

#define RD_A(DST, MB, dd)                                                     \
  _Pragma("unroll") for (int mf = 0; mf < 4; ++mf)                            \
  _Pragma("unroll") for (int kk = 0; kk < 2; ++kk)                            \
    DST[mf][kk] = *(const bf16x8*)&As[dd][(arb + (MB) * 64 + mf * 16) * 64 +  \
                                          (((kk * 4 + hi) ^ rsw) << 3)];
#define RD_B(DST, NB, NCNT, dd)                                               \
  _Pragma("unroll") for (int nf = 0; nf < (NCNT); ++nf)                       \
  _Pragma("unroll") for (int kk = 0; kk < 2; ++kk)                            \
    DST[nf][kk] = *(const bf16x8*)&Bs[dd][(bcb + ((NB) + nf) * 16) * 64 +     \
                                          (((kk * 4 + hi) ^ rsw) << 3)];
#define MFMA_Q(AF, BF, MB, NB, NCNT)                                          \
  _Pragma("unroll") for (int mf = 0; mf < 4; ++mf)                            \
  _Pragma("unroll") for (int nf = 0; nf < (NCNT); ++nf)                       \
  _Pragma("unroll") for (int kk = 0; kk < 2; ++kk)                            \
    acc[(MB) + mf][(NB) + nf] = __builtin_amdgcn_mfma_f32_16x16x32_bf16(      \
        AF[mf][kk], BF[nf][kk], acc[(MB) + mf][(NB) + nf], 0, 0, 0);

#define LGKM0  asm volatile("s_waitcnt lgkmcnt(0)" ::: "memory")
#define LGKM8  asm volatile("s_waitcnt lgkmcnt(8)" ::: "memory")
#define VMW(N) asm volatile("s_waitcnt vmcnt(" #N ")" ::: "memory")
#define BARR   __builtin_amdgcn_s_barrier()
#define PRIO1  __builtin_amdgcn_s_setprio(1)
#define PRIO0  __builtin_amdgcn_s_setprio(0)

  const int NT = K >> 6;          // even by construction

  // ---- prologue: A[0],B[0] -> buf0; B[1] -> buf1 stays in flight
  stA(0, 0, 0); stA(0, 1, 0); stA(0, 2, 0); stA(0, 3, 0);
  stB(0, 0, 0); stB(0, 1, 0); stB(0, 2, 0); stB(0, 3, 0); stB(0, 4, 0);
  stB(1, 0, 64); stB(1, 1, 64); stB(1, 2, 64); stB(1, 3, 64); stB(1, 4, 64);
  VMW(5);
  BARR;

  for (int it = 0; it < (NT >> 1); ++it) {
    const int  T   = it * 2;
    const long k1  = (long)(T + 1) * 64;
    const long k2  = (long)(T + 2) * 64;
    const long k3  = (long)(T + 3) * 64;
    const bool pf2 = (T + 2 < NT);
    const bool pf3 = (T + 3 < NT);

    // P1: alo(8)+b01(4) reads; stage A[T+1] g0,g1
    RD_A(alo, 0, 0); RD_B(b01, 0, 2, 0);
    stA(1, 0, k1); stA(1, 1, k1);
    LGKM8;
    BARR; LGKM0; PRIO1; MFMA_Q(alo, b01, 0, 0, 2); PRIO0; BARR;

    // P2: b234(6) reads; stage A[T+1] g2,g3
    RD_B(b234, 2, 3, 0);
    stA(1, 2, k1); stA(1, 3, k1);
    BARR; LGKM0; PRIO1; MFMA_Q(alo, b234, 0, 2, 3); PRIO0; BARR;

    // P3: ahi(8) reads; stage B[T+2] g0,g1 (B[T] reads done @P2-close)
    RD_A(ahi, 1, 0);
    if (pf2) { stB(0, 0, k2); stB(0, 1, k2); }
    BARR; LGKM0; PRIO1; MFMA_Q(ahi, b234, 4, 2, 3); PRIO0; BARR;

    // P4: no reads; stage B[T+2] g2,g3,g4; counted wait
    if (pf2) { stB(0, 2, k2); stB(0, 3, k2); stB(0, 4, k2); }
    PRIO1; MFMA_Q(ahi, b01, 4, 0, 2); PRIO0;
    if (pf2) { VMW(5); } else { VMW(0); }
    BARR;

    // P5: tile T+1 (buf1); stage A[T+2] g0,g1 (A[T] reads done @P3-close)
    RD_A(alo, 0, 1); RD_B(b01, 0, 2, 1);
    if (pf2) { stA(0, 0, k2); stA(0, 1, k2); }
    LGKM8;
    BARR; LGKM0; PRIO1; MFMA_Q(alo, b01, 0, 0, 2); PRIO0; BARR;

    // P6: stage A[T+2] g2,g3
    RD_B(b234, 2, 3, 1);
    if (pf2) { stA(0, 2, k2); stA(0, 3, k2); }
    BARR; LGKM0; PRIO1; MFMA_Q(alo, b234, 0, 2, 3); PRIO0; BARR;

    // P7: stage B[T+3] g0,g1 (B[T+1] reads done @P6-close)
    RD_A(ahi, 1, 1);
    if (pf3) { stB(1, 0, k3); stB(1, 1, k3); }
    BARR; LGKM0; PRIO1; MFMA_Q(ahi, b234, 4, 2, 3); PRIO0; BARR;

    // P8: stage B[T+3] g2,g3,g4; counted wait
    if (pf3) { stB(1, 2, k3); stB(1, 3, k3); stB(1, 4, k3); }
    PRIO1; MFMA_Q(ahi, b01, 4, 0, 2); PRIO0;
    if (pf2) { VMW(5); BARR; }            // last iter: nothing left to read
  }

  // epilogue: C/D layout col=lane&15, row=(lane>>4)*4+reg
  if (MODE == 0) {
#pragma unroll
    for (int nf = 0; nf < 5; ++nf) {
      const int colg = bcol + wn * 80 + nf * 16 + lr;
      float s = 0.f, s2 = 0.f;
#pragma unroll
      for (int mf = 0; mf < 8; ++mf) {
        const int rowg = brow + wm * 128 + mf * 16 + hi * 4;
#pragma unroll
        for (int r = 0; r < 4; ++r) {
          float v = acc[mf][nf][r];
          s += v; s2 += v * v;
          Cb[(size_t)(rowg + r) * Npad + colg] = (bf16_t)v;
        }
      }
      s  += __shfl_xor(s, 16, 64);  s  += __shfl_xor(s, 32, 64);
      s2 += __shfl_xor(s2, 16, 64); s2 += __shfl_xor(s2, 32, 64);
      if (lane < 16) {
        atomicAdd(&sum[colg], s);
        atomicAdd(&sq[colg], s2);
      }
    }
  } else {
#pragma unroll
    for (int nf = 0; nf < 5; ++nf) {
      const int colg = bcol + wn * 80 + nf * 16 + lr;
      if (colg < Nvalid) {
#pragma unroll
        for (int mf = 0; mf < 8; ++mf) {
          const int rowg = brow + wm * 128 + mf * 16 + hi * 4;
#pragma unroll
          for (int r = 0; r < 4; ++r)
            Cf[(size_t)(rowg + r) * Nvalid + colg] = acc[mf][nf][r];
        }
      }
    }
  }
#undef RD_A
#undef RD_B
#undef MFMA_Q
#undef LGKM0
#undef LGKM8
#undef VMW
#undef BARR
#undef PRIO1
#undef PRIO0
}

// =======================================================================
// 128x128 4-wave GEMM (r2 structure) — for the smaller GEMMs
// =======================================================================
template<int MODE>
__global__ __launch_bounds__(256, 2)
void gemm_bt(const bf16_t* __restrict__ A, const bf16_t* __restrict__ Bm,
             int K, bf16_t* __restrict__ Cb, int Npad,
             float* __restrict__ sum, float* __restrict__ sq,
             float* __restrict__ Cf, int Nvalid)
{
  __shared__ bf16_t As[128 * 64];
  __shared__ bf16_t Bs[128 * 64];
  const int tid  = threadIdx.x;
  const int wave = tid >> 6;
  const int lane = tid & 63;

  int wg = xcd_swizzle((int)blockIdx.x + (int)blockIdx.y * gridDim.x,
                       gridDim.x * gridDim.y);
  const int brow = (wg / gridDim.x) * 128;
  const int bcol = (wg % gridDim.x) * 128;

  const int wrow = (wave >> 1) * 64;
  const int wcol = (wave & 1) * 64;

  const int rr  = tid >> 3;                         // 0..31
  const int cc  = (((tid & 7) ^ (rr & 7)) << 3);    // swizzled 8-elem granule

  const bf16_t* ga[4];
  const bf16_t* gb[4];
#pragma unroll
  for (int i = 0; i < 4; ++i) {
    ga[i] = A  + (size_t)(brow + i * 32 + rr) * K + cc;
    gb[i] = Bm + (size_t)(bcol + i * 32 + rr) * K + cc;
  }
  bf16_t* lab = As + wave * 512;
  bf16_t* lbb = Bs + wave * 512;

  f32x4 acc[4][4] = {};

  const int lr  = lane & 15;
  const int g0  = lane >> 4;
  const int rsw = lr & 7;

  for (int kt = 0; kt < K; kt += 64) {
#pragma unroll
    for (int i = 0; i < 4; ++i) {
      load_lds16(ga[i] + kt, lab + i * 2048);
      load_lds16(gb[i] + kt, lbb + i * 2048);
    }
    __syncthreads();
#pragma unroll
    for (int kk = 0; kk < 2; ++kk) {
      const int swz = (((kk * 4 + g0) ^ rsw) << 3);
      bf16x8 af[4], bfr[4];
#pragma unroll
      for (int mi = 0; mi < 4; ++mi)
        af[mi] = *(const bf16x8*)(As + (wrow + mi * 16 + lr) * 64 + swz);
#pragma unroll
      for (int ni = 0; ni < 4; ++ni)
        bfr[ni] = *(const bf16x8*)(Bs + (wcol + ni * 16 + lr) * 64 + swz);
#pragma unroll
      for (int mi = 0; mi < 4; ++mi)
#pragma unroll
        for (int ni = 0; ni < 4; ++ni)
          acc[mi][ni] = __builtin_amdgcn_mfma_f32_16x16x32_bf16(af[mi], bfr[ni], acc[mi][ni], 0, 0, 0);
    }
    __syncthreads();
  }

  const int lcol = lane & 15;
  const int lrow = (lane >> 4) * 4;
  if (MODE == 0) {
#pragma unroll
    for (int ni = 0; ni < 4; ++ni) {
      const int colg = bcol + wcol + ni * 16 + lcol;
      float s = 0.f, s2 = 0.f;
#pragma unroll
      for (int mi = 0; mi < 4; ++mi) {
        const int rowg = brow + wrow + mi * 16 + lrow;
#pragma unroll
        for (int r = 0; r < 4; ++r) {
          float v = acc[mi][ni][r];
          s += v; s2 += v * v;
          Cb[(size_t)(rowg + r) * Npad + colg] = (bf16_t)v;
        }
      }
      s  += __shfl_xor(s, 16, 64);  s  += __shfl_xor(s, 32, 64);
      s2 += __shfl_xor(s2, 16, 64); s2 += __shfl_xor(s2, 32, 64);
      if (lane < 16) {
        atomicAdd(&sum[colg], s);
        atomicAdd(&sq[colg], s2);
      }
    }
  } else {
#pragma unroll
    for (int ni = 0; ni < 4; ++ni) {
      const int colg = bcol + wcol + ni * 16 + lcol;
      if (colg < Nvalid) {
#pragma unroll
        for (int mi = 0; mi < 4; ++mi) {
          const int rowg = brow + wrow + mi * 16 + lrow;
#pragma unroll
          for (int r = 0; r < 4; ++r)
            Cf[(size_t)(rowg + r) * Nvalid + colg] = acc[mi][ni][r];
        }
      }
    }
  }
}

// ---------------- prep: out[npad][kpad] = bf16(W*mask), zero-padded ----------------
__global__ void k_prep(const float* __restrict__ W, const float* __restrict__ Mk,
                       bf16_t* __restrict__ out, int N, int K, int Npad, int Kpad)
{
  const int  kg    = Kpad >> 3;
  const long total = (long)Npad * kg;
  for (long idx = (long)blockIdx.x * blockDim.x + threadIdx.x; idx < total;
       idx += (long)gridDim.x * blockDim.x) {
    const int n = (int)(idx / kg);
    const int c = (int)(idx % kg) * 8;
    bf16x8 o;
#pragma unroll
    for (int j = 0; j < 8; ++j) o[j] = (bf16_t)0.f;
    if (n < N && c < K) {               // K % 8 == 0 for all inputs
      const f32x4* w4 = (const f32x4*)(W + (size_t)n * K + c);
      f32x4 a = w4[0], b = w4[1];
      if (Mk) {
        const f32x4* m4 = (const f32x4*)(Mk + (size_t)n * K + c);
        f32x4 ma = m4[0], mb = m4[1];
        a *= ma; b *= mb;
      }
#pragma unroll
      for (int j = 0; j < 4; ++j) { o[j] = (bf16_t)a[j]; o[4 + j] = (bf16_t)b[j]; }
    }
    *(bf16x8*)(out + (size_t)idx * 8) = o;
  }
}

// ---------------- BN finalize: sum->scale, sq->shift ----------------
__global__ void k_finalize(float* __restrict__ sum, float* __restrict__ sq,
                           const float* __restrict__ g, const float* __restrict__ be,
                           int Nvalid, int Npad)
{
  const int c = blockIdx.x * blockDim.x + threadIdx.x;
  if (c >= Npad) return;
  float sc = 0.f, sh = 0.f;
  if (c < Nvalid) {
    const float invM = 1.0f / 8192.0f;
    float mean = sum[c] * invM;
    float var  = sq[c] * invM - mean * mean;
    sc = g[c] * rsqrtf(var + 1e-3f);
    sh = be[c] - mean * sc;
  }
  sum[c] = sc; sq[c] = sh;
}

// ---------------- BN apply (+optional ELU, optional f32 out) ----------------
__global__ void k_bn_elu(const bf16_t* __restrict__ pre, const float* __restrict__ sc,
                         const float* __restrict__ sh, bf16_t* __restrict__ outb,
                         float* __restrict__ outf, int Nvalid, int Npad, int elu)
{
  const int  ng    = Npad >> 3;
  const long total = (long)B_ROWS * ng;
  for (long idx = (long)blockIdx.x * blockDim.x + threadIdx.x; idx < total;
       idx += (long)gridDim.x * blockDim.x) {
    const int r = (int)(idx / ng);
    const int c = (int)(idx % ng) * 8;
    bf16x8 o;
#pragma unroll
    for (int j = 0; j < 8; ++j) o[j] = (bf16_t)0.f;
    if (c < Nvalid) {                   // Nvalid % 8 == 0 -> group fully valid
      bf16x8 x = *(const bf16x8*)(pre + (size_t)r * Npad + c);
      f32x4 y0, y1;
#pragma unroll
      for (int j = 0; j < 8; ++j) {
        float v = (float)x[j] * sc[c + j] + sh[c + j];
        if (elu) v = v > 0.f ? v : expm1f(v);
        if (j < 4) y0[j] = v; else y1[j - 4] = v;
        o[j] = (bf16_t)v;
      }
      if (outf) {
        float* p = outf + (size_t)r * Nvalid + c;
        *(f32x4*)p       = y0;
        *(f32x4*)(p + 4) = y1;
      }
    }
    *(bf16x8*)(outb + (size_t)r * Npad + c) = o;
  }
}

// ---------------- reparametrize: mu/logvar/z f32 out + z bf16 (padded) ----------------
__global__ void k_reparam(const bf16_t* __restrict__ p, const float* __restrict__ sc,
                          const float* __restrict__ sh, const float* __restrict__ eps,
                          float* __restrict__ z, float* __restrict__ mu,
                          float* __restrict__ lv, bf16_t* __restrict__ zb)
{
  const long total = (long)B_ROWS * (LTP / 4);
  for (long idx = (long)blockIdx.x * blockDim.x + threadIdx.x; idx < total;
       idx += (long)gridDim.x * blockDim.x) {
    const int r = (int)(idx / (LTP / 4));
    const int j = (int)(idx % (LTP / 4)) * 4;
    if (j < LT) {                       // LT % 4 == 0
      bf16x4 pm = *(const bf16x4*)(p + (size_t)r * H2P + j);
      bf16x4 pl = *(const bf16x4*)(p + (size_t)r * H2P + LT + j);
      f32x4  e  = *(const f32x4*)(eps + (size_t)r * LT + j);
      f32x4 mv, lvv, zv; bf16x4 z4;
#pragma unroll
      for (int t = 0; t < 4; ++t) {
        float m_ = (float)pm[t] * sc[j + t] + sh[j + t];
        float l_ = (float)pl[t] * sc[LT + j + t] + sh[LT + j + t];
        float zz = fmaf(expf(l_ * 0.5f), e[t], m_);
        mv[t] = m_; lvv[t] = l_; zv[t] = zz; z4[t] = (bf16_t)zz;
      }
      *(f32x4*)(mu + (size_t)r * LT + j) = mv;
      *(f32x4*)(lv + (size_t)r * LT + j) = lvv;
      *(f32x4*)(z  + (size_t)r * LT + j) = zv;
      *(bf16x4*)(zb + (size_t)r * LTP + j) = z4;
    } else {
      bf16x4 z4;
#pragma unroll
      for (int t = 0; t < 4; ++t) z4[t] = (bf16_t)0.f;
      *(bf16x4*)(zb + (size_t)r * LTP + j) = z4;
    }
  }
}

// ---------------- host ----------------
extern "C" void kernel_launch(void* const* d_in, const int* in_sizes, int n_in,
                              void* d_out, int out_size, void* d_ws, size_t ws_size,
                              hipStream_t stream)
{
  const float* x     = (const float*)d_in[0];
  const float* eps   = (const float*)d_in[1];
  const float* mask1 = (const float*)d_in[2];
  const float* mask2 = (const float*)d_in[3];
  const float* maskd = (const float*)d_in[4];
  const float* maskm = (const float*)d_in[5];
  const float* W1    = (const float*)d_in[6];
  // b1 (d_in[7]) cancels in BN (mean subtraction) -> unused
  const float* g1    = (const float*)d_in[8];
  const float* be1   = (const float*)d_in[9];
  const float* W2    = (const float*)d_in[10];
  // b2 (d_in[11]) cancels in BN
  const float* g2    = (const float*)d_in[12];
  const float* be2   = (const float*)d_in[13];
  const float* Wd    = (const float*)d_in[14];
  // bd (d_in[15]) cancels in BN
  const float* gd    = (const float*)d_in[16];
  const float* bed   = (const float*)d_in[17];
  const float* Wm    = (const float*)d_in[18];
  float* out = (float*)d_out;
  char*  ws  = (char*)d_ws;

  // workspace layout (aliased where lifetimes are disjoint)
  size_t off = 0;
  auto alloc = [&](size_t bytes) { size_t o = off; off += (bytes + 255) & ~(size_t)255; return o; };
  const size_t XBF  = alloc((size_t)B_ROWS * GENP * 2);  // x bf16; later mo_bf16
  const size_t W1M  = alloc((size_t)H1P * GENP * 2);     // W1 masked; later p_pre
  const size_t W2M  = alloc((size_t)H2P * H1P * 2);
  const size_t WDM  = alloc((size_t)H1P * LTP * 2);
  const size_t WMM  = alloc((size_t)GENP * H1P * 2);
  const size_t HPRE = alloc((size_t)B_ROWS * H1P * 2);   // h_pre; later d_pre
  const size_t HBF  = alloc((size_t)B_ROWS * H1P * 2);   // h bf16; later z bf16
  const size_t STAT = alloc((size_t)(H1P + H2P + H1P) * 2 * sizeof(float));
  if (ws_size < off) {
    fprintf(stderr, "kernel_launch: workspace too small: need %zu have %zu\n", off, ws_size);
    return;
  }

  bf16_t* xb   = (bf16_t*)(ws + XBF);
  bf16_t* w1m  = (bf16_t*)(ws + W1M);
  bf16_t* w2m  = (bf16_t*)(ws + W2M);
  bf16_t* wdm  = (bf16_t*)(ws + WDM);
  bf16_t* wmm  = (bf16_t*)(ws + WMM);
  bf16_t* hpre = (bf16_t*)(ws + HPRE);
  bf16_t* hbf  = (bf16_t*)(ws + HBF);
  bf16_t* ppre = (bf16_t*)(ws + W1M);   // alias: W1 masked dead after GEMM1
  bf16_t* zbf  = (bf16_t*)(ws + HBF);   // alias: h bf16 dead after GEMM2
  bf16_t* dpre = (bf16_t*)(ws + HPRE);  // alias: h_pre dead after BN1 apply
  bf16_t* mobf = (bf16_t*)(ws + XBF);   // alias: x bf16 dead after GEMM1

  float* s1 = (float*)(ws + STAT);
  float* q1 = s1 + H1P;
  float* s2 = q1 + H1P;
  float* q2 = s2 + H2P;
  float* sd = q2 + H2P;
  float* qd = sd + H1P;

  float* o_recon = out;
  float* o_z     = o_recon + (size_t)B_ROWS * GEN;
  float* o_mo    = o_z     + (size_t)B_ROWS * LT;
  float* o_mu    = o_mo    + (size_t)B_ROWS * H1;
  float* o_lv    = o_mu    + (size_t)B_ROWS * LT;

  hipMemsetAsync(ws + STAT, 0, (size_t)(H1P + H2P + H1P) * 2 * sizeof(float), stream);

  // prep: cast/mask to bf16, zero-padded
  k_prep<<<2048, 256, 0, stream>>>(x,  nullptr, xb,  B_ROWS, GEN, B_ROWS, GENP);
  k_prep<<<2048, 256, 0, stream>>>(W1, mask1,   w1m, H1,  GEN, H1P,  GENP);
  k_prep<<<2048, 256, 0, stream>>>(W2, mask2,   w2m, H2,  H1,  H2P,  H1P);
  k_prep<<<2048, 256, 0, stream>>>(Wd, maskd,   wdm, H1,  LT,  H1P,  LTP);
  k_prep<<<2048, 256, 0, stream>>>(Wm, maskm,   wmm, GEN, H1,  GENP, H1P);

  // encoder L1: h_pre = x @ W1m^T  (+ batch stats)  [256x320 8-phase, grid 448]
  gemm256<0><<<dim3(H1P / 320, B_ROWS / 256), 512, 0, stream>>>(
      xb, w1m, GENP, hpre, H1P, s1, q1, nullptr, 0);
  k_finalize<<<(H1P + 255) / 256, 256, 0, stream>>>(s1, q1, g1, be1, H1, H1P);
  k_bn_elu<<<2048, 256, 0, stream>>>(hpre, s1, q1, hbf, nullptr, H1, H1P, 1);

  // encoder L2: p_pre = h @ W2m^T (+ stats), then reparametrize  [128^2]
  gemm_bt<0><<<dim3(H2P / 128, B_ROWS / 128), 256, 0, stream>>>(
      hbf, w2m, H1P, ppre, H2P, s2, q2, nullptr, 0);
  k_finalize<<<(H2P + 255) / 256, 256, 0, stream>>>(s2, q2, g2, be2, H2, H2P);
  k_reparam<<<2048, 256, 0, stream>>>(ppre, s2, q2, eps, o_z, o_mu, o_lv, zbf);

  // decoder: d_pre = z @ Wdm^T (+ stats), BN+ELU -> module_outputs  [128^2]
  gemm_bt<0><<<dim3(H1P / 128, B_ROWS / 128), 256, 0, stream>>>(
      zbf, wdm, LTP, dpre, H1P, sd, qd, nullptr, 0);
  k_finalize<<<(H1P + 255) / 256, 256, 0, stream>>>(sd, qd, gd, bed, H1, H1P);
  k_bn_elu<<<2048, 256, 0, stream>>>(dpre, sd, qd, mobf, o_mo, H1, H1P, 1);

  // merger: global_recon = mo @ Wmm^T (f32 out, no BN)  [256x320, grid 512 = 2 full rounds]
  gemm256<1><<<dim3(GENP / 320, B_ROWS / 256), 512, 0, stream>>>(
      mobf, wmm, H1P, nullptr, 0, nullptr, nullptr, o_recon, GEN);
}

// Round 6
// 1288.227 us; speedup vs baseline: 1.7768x; 1.7768x over previous
//
#include <hip/hip_runtime.h>
#include <cstdio>
#include <cstdint>

typedef __bf16 bf16_t;
typedef __bf16 bf16x8 __attribute__((ext_vector_type(8)));
typedef __bf16 bf16x4 __attribute__((ext_vector_type(4)));
typedef float  f32x4  __attribute__((ext_vector_type(4)));

// problem dims
#define B_ROWS 8192
#define GEN    5000
#define GENP   5120   // padded K for gemm1 / N for merger
#define H1     4128
#define H1P    4224   // mult of 128 (gemm N) and 64 (K)
#define H2     2064
#define LT     1032
#define NMOD   129    // pathway modules (incl. aux)

// ---------------- async global->LDS helper ----------------
__device__ __forceinline__ void load_lds16(const bf16_t* g, bf16_t* l) {
  __builtin_amdgcn_global_load_lds((__attribute__((address_space(1))) void*)g,
                                   (__attribute__((address_space(3))) void*)l,
                                   16, 0, 0);
}

__device__ __forceinline__ int xcd_swizzle(int wg, int nwg) {
  const int q = nwg >> 3, r8 = nwg & 7;
  const int xcd = wg & 7, sidx = wg >> 3;
  return (xcd < r8 ? xcd * (q + 1) : r8 * (q + 1) + (xcd - r8) * q) + sidx;
}

// =======================================================================
// 128x128 4-wave GEMM (round-2 structure, best measured): C = A * B^T
// granule-XOR LDS swizzle via pre-swizzled global source (T2, conflicts=0)
// MODE 0: bf16 C (ld Npad) + per-column sum/sumsq atomics (BN stats)
// MODE 1: f32 C (ld Nvalid, col-bounded)
// =======================================================================
template<int MODE>
__global__ __launch_bounds__(256, 2)
void gemm_bt(const bf16_t* __restrict__ A, const bf16_t* __restrict__ Bm,
             int K, bf16_t* __restrict__ Cb, int Npad,
             float* __restrict__ sum, float* __restrict__ sq,
             float* __restrict__ Cf, int Nvalid)
{
  __shared__ bf16_t As[128 * 64];
  __shared__ bf16_t Bs[128 * 64];
  const int tid  = threadIdx.x;
  const int wave = tid >> 6;
  const int lane = tid & 63;

  int wg = xcd_swizzle((int)blockIdx.x + (int)blockIdx.y * gridDim.x,
                       gridDim.x * gridDim.y);
  const int brow = (wg / gridDim.x) * 128;
  const int bcol = (wg % gridDim.x) * 128;

  const int wrow = (wave >> 1) * 64;
  const int wcol = (wave & 1) * 64;

  const int rr  = tid >> 3;                         // 0..31
  const int cc  = (((tid & 7) ^ (rr & 7)) << 3);    // swizzled 8-elem granule

  const bf16_t* ga[4];
  const bf16_t* gb[4];
#pragma unroll
  for (int i = 0; i < 4; ++i) {
    ga[i] = A  + (size_t)(brow + i * 32 + rr) * K + cc;
    gb[i] = Bm + (size_t)(bcol + i * 32 + rr) * K + cc;
  }
  bf16_t* lab = As + wave * 512;
  bf16_t* lbb = Bs + wave * 512;

  f32x4 acc[4][4] = {};

  const int lr  = lane & 15;
  const int g0  = lane >> 4;
  const int rsw = lr & 7;

  for (int kt = 0; kt < K; kt += 64) {
#pragma unroll
    for (int i = 0; i < 4; ++i) {
      load_lds16(ga[i] + kt, lab + i * 2048);
      load_lds16(gb[i] + kt, lbb + i * 2048);
    }
    __syncthreads();
#pragma unroll
    for (int kk = 0; kk < 2; ++kk) {
      const int swz = (((kk * 4 + g0) ^ rsw) << 3);
      bf16x8 af[4], bfr[4];
#pragma unroll
      for (int mi = 0; mi < 4; ++mi)
        af[mi] = *(const bf16x8*)(As + (wrow + mi * 16 + lr) * 64 + swz);
#pragma unroll
      for (int ni = 0; ni < 4; ++ni)
        bfr[ni] = *(const bf16x8*)(Bs + (wcol + ni * 16 + lr) * 64 + swz);
#pragma unroll
      for (int mi = 0; mi < 4; ++mi)
#pragma unroll
        for (int ni = 0; ni < 4; ++ni)
          acc[mi][ni] = __builtin_amdgcn_mfma_f32_16x16x32_bf16(af[mi], bfr[ni], acc[mi][ni], 0, 0, 0);
    }
    __syncthreads();
  }

  const int lcol = lane & 15;
  const int lrow = (lane >> 4) * 4;
  if (MODE == 0) {
#pragma unroll
    for (int ni = 0; ni < 4; ++ni) {
      const int colg = bcol + wcol + ni * 16 + lcol;
      float s = 0.f, s2 = 0.f;
#pragma unroll
      for (int mi = 0; mi < 4; ++mi) {
        const int rowg = brow + wrow + mi * 16 + lrow;
#pragma unroll
        for (int r = 0; r < 4; ++r) {
          float v = acc[mi][ni][r];
          s += v; s2 += v * v;
          Cb[(size_t)(rowg + r) * Npad + colg] = (bf16_t)v;
        }
      }
      s  += __shfl_xor(s, 16, 64);  s  += __shfl_xor(s, 32, 64);
      s2 += __shfl_xor(s2, 16, 64); s2 += __shfl_xor(s2, 32, 64);
      if (lane < 16) {
        atomicAdd(&sum[colg], s);
        atomicAdd(&sq[colg], s2);
      }
    }
  } else {
#pragma unroll
    for (int ni = 0; ni < 4; ++ni) {
      const int colg = bcol + wcol + ni * 16 + lcol;
      if (colg < Nvalid) {
#pragma unroll
        for (int mi = 0; mi < 4; ++mi) {
          const int rowg = brow + wrow + mi * 16 + lrow;
#pragma unroll
          for (int r = 0; r < 4; ++r)
            Cf[(size_t)(rowg + r) * Nvalid + colg] = acc[mi][ni][r];
        }
      }
    }
  }
}

// ---------------- prep: out[npad][kpad] = bf16(W*mask), zero-padded ----------------
__global__ void k_prep(const float* __restrict__ W, const float* __restrict__ Mk,
                       bf16_t* __restrict__ out, int N, int K, int Npad, int Kpad)
{
  const int  kg    = Kpad >> 3;
  const long total = (long)Npad * kg;
  for (long idx = (long)blockIdx.x * blockDim.x + threadIdx.x; idx < total;
       idx += (long)gridDim.x * blockDim.x) {
    const int n = (int)(idx / kg);
    const int c = (int)(idx % kg) * 8;
    bf16x8 o;
#pragma unroll
    for (int j = 0; j < 8; ++j) o[j] = (bf16_t)0.f;
    if (n < N && c < K) {               // K % 8 == 0 for all inputs
      const f32x4* w4 = (const f32x4*)(W + (size_t)n * K + c);
      f32x4 a = w4[0], b = w4[1];
      if (Mk) {
        const f32x4* m4 = (const f32x4*)(Mk + (size_t)n * K + c);
        f32x4 ma = m4[0], mb = m4[1];
        a *= ma; b *= mb;
      }
#pragma unroll
      for (int j = 0; j < 4; ++j) { o[j] = (bf16_t)a[j]; o[4 + j] = (bf16_t)b[j]; }
    }
    *(bf16x8*)(out + (size_t)idx * 8) = o;
  }
}

// ---------------- BN finalize: sum->scale, sq->shift ----------------
__global__ void k_finalize(float* __restrict__ sum, float* __restrict__ sq,
                           const float* __restrict__ g, const float* __restrict__ be,
                           int Nvalid, int Npad)
{
  const int c = blockIdx.x * blockDim.x + threadIdx.x;
  if (c >= Npad) return;
  float sc = 0.f, sh = 0.f;
  if (c < Nvalid) {
    const float invM = 1.0f / 8192.0f;
    float mean = sum[c] * invM;
    float var  = sq[c] * invM - mean * mean;
    sc = g[c] * rsqrtf(var + 1e-3f);
    sh = be[c] - mean * sc;
  }
  sum[c] = sc; sq[c] = sh;
}

// ---------------- BN apply (+optional ELU, optional f32 out) ----------------
__global__ void k_bn_elu(const bf16_t* __restrict__ pre, const float* __restrict__ sc,
                         const float* __restrict__ sh, bf16_t* __restrict__ outb,
                         float* __restrict__ outf, int Nvalid, int Npad, int elu)
{
  const int  ng    = Npad >> 3;
  const long total = (long)B_ROWS * ng;
  for (long idx = (long)blockIdx.x * blockDim.x + threadIdx.x; idx < total;
       idx += (long)gridDim.x * blockDim.x) {
    const int r = (int)(idx / ng);
    const int c = (int)(idx % ng) * 8;
    bf16x8 o;
#pragma unroll
    for (int j = 0; j < 8; ++j) o[j] = (bf16_t)0.f;
    if (c < Nvalid) {                   // Nvalid % 8 == 0 -> group fully valid
      bf16x8 x = *(const bf16x8*)(pre + (size_t)r * Npad + c);
      f32x4 y0, y1;
#pragma unroll
      for (int j = 0; j < 8; ++j) {
        float v = (float)x[j] * sc[c + j] + sh[c + j];
        if (elu) v = v > 0.f ? v : expm1f(v);
        if (j < 4) y0[j] = v; else y1[j - 4] = v;
        o[j] = (bf16_t)v;
      }
      if (outf) {
        float* p = outf + (size_t)r * Nvalid + c;
        *(f32x4*)p       = y0;
        *(f32x4*)(p + 4) = y1;
      }
    }
    *(bf16x8*)(outb + (size_t)r * Npad + c) = o;
  }
}

// =======================================================================
// k_enc2: block-diagonal encoder L2, fused BN1+ELU.
// mask2 row r (module m = (r%1032)/8) is nonzero only on cols [m*32, m*32+32).
// Block = (module m, 256-row chunk). Per thread (one batch row):
//   h = elu(bn1(hpre[b, m*32..+32])); p[i] = sum_j W2blk[i][j]*h[j], i<16
//   (i<8 -> mu row m*8+i, i>=8 -> lv row 1032+m*8+(i-8))
// Writes pp module-major: pp[(m*8192+b)*16 + i] (bf16). Stats via LDS
// transpose + wave butterfly -> 32 atomics/block.
// =======================================================================
__global__ __launch_bounds__(256)
void k_enc2(const bf16_t* __restrict__ hpre,
            const float* __restrict__ sc1, const float* __restrict__ sh1,
            const float* __restrict__ W2,
            bf16_t* __restrict__ pp,
            float* __restrict__ s2, float* __restrict__ q2)
{
  __shared__ float ws2[16][32];
  __shared__ float lsc[32], lsh[32];
  __shared__ float dbuf[256][17];
  __shared__ float part[2][4][16];
  const int m = blockIdx.x;
  const int t = threadIdx.x;
  const int b = blockIdx.y * 256 + t;

  for (int i = t; i < 512; i += 256) {
    const int r = i >> 5, j = i & 31;
    const int grow = (r < 8) ? (m * 8 + r) : (LT + m * 8 + (r - 8));
    ws2[r][j] = W2[(size_t)grow * H1 + m * 32 + j];
  }
  if (t < 32) lsc[t] = sc1[m * 32 + t];
  else if (t < 64) lsh[t - 32] = sh1[m * 32 + (t - 32)];
  __syncthreads();

  float h[32];
  const bf16_t* hp = hpre + (size_t)b * H1P + m * 32;
#pragma unroll
  for (int v = 0; v < 4; ++v) {
    bf16x8 x = *(const bf16x8*)(hp + v * 8);
#pragma unroll
    for (int j = 0; j < 8; ++j) {
      float val = (float)x[j] * lsc[v * 8 + j] + lsh[v * 8 + j];
      h[v * 8 + j] = val > 0.f ? val : expm1f(val);
    }
  }

  float p[16];
#pragma unroll
  for (int i = 0; i < 16; ++i) {
    float a = 0.f;
#pragma unroll
    for (int jb = 0; jb < 8; ++jb) {
      f32x4 w = *(const f32x4*)&ws2[i][jb * 4];
      a = fmaf(w[0], h[jb * 4 + 0], a);
      a = fmaf(w[1], h[jb * 4 + 1], a);
      a = fmaf(w[2], h[jb * 4 + 2], a);
      a = fmaf(w[3], h[jb * 4 + 3], a);
    }
    p[i] = a;
  }

  bf16x8 o0, o1;
#pragma unroll
  for (int i = 0; i < 8; ++i) { o0[i] = (bf16_t)p[i]; o1[i] = (bf16_t)p[8 + i]; }
  bf16_t* pw = pp + ((size_t)m * B_ROWS + b) * 16;
  *(bf16x8*)pw = o0; *(bf16x8*)(pw + 8) = o1;

  // stats
#pragma unroll
  for (int i = 0; i < 16; ++i) dbuf[t][i] = p[i];
  __syncthreads();
  {
    const int col = t & 15, sl = t >> 4;   // 16 slices of 16 rows
    float s = 0.f, q = 0.f;
#pragma unroll
    for (int r = 0; r < 16; ++r) {
      float v = dbuf[sl * 16 + r][col];
      s += v; q += v * v;
    }
    s += __shfl_xor(s, 16, 64); s += __shfl_xor(s, 32, 64);
    q += __shfl_xor(q, 16, 64); q += __shfl_xor(q, 32, 64);
    const int w = t >> 6;
    if ((t & 63) < 16) { part[0][w][col] = s; part[1][w][col] = q; }
    __syncthreads();
    if (t < 16) {
      float ss = part[0][0][t] + part[0][1][t] + part[0][2][t] + part[0][3][t];
      float qq = part[1][0][t] + part[1][1][t] + part[1][2][t] + part[1][3][t];
      const int gc = (t < 8) ? (m * 8 + t) : (LT + m * 8 + (t - 8));
      atomicAdd(&s2[gc], ss);
      atomicAdd(&q2[gc], qq);
    }
  }
}

// =======================================================================
// k_dec: fused BN2 + reparametrize + block-diagonal decoder L1.
// maskd row (m*32+j) nonzero only on cols [m*8, m*8+8).
// Writes o_z/o_mu/o_lv (f32, reference layout), dpre bf16 (ld H1P, real
// cols only), and BN-d stats.
// =======================================================================
__global__ __launch_bounds__(256)
void k_dec(const bf16_t* __restrict__ pp,
           const float* __restrict__ sc2, const float* __restrict__ sh2,
           const float* __restrict__ eps, const float* __restrict__ Wd,
           float* __restrict__ o_z, float* __restrict__ o_mu, float* __restrict__ o_lv,
           bf16_t* __restrict__ dpre,
           float* __restrict__ sd, float* __restrict__ qd)
{
  __shared__ float wd[32][8];
  __shared__ float lsc[16], lsh[16];
  __shared__ float dbuf[256][33];
  __shared__ float part[2][4][32];
  const int m = blockIdx.x;
  const int t = threadIdx.x;
  const int b = blockIdx.y * 256 + t;

  {
    const int j = t >> 3, l = t & 7;
    wd[j][l] = Wd[(size_t)(m * 32 + j) * LT + m * 8 + l];
  }
  if (t < 16) {
    const int gc = (t < 8) ? (m * 8 + t) : (LT + m * 8 + (t - 8));
    lsc[t] = sc2[gc]; lsh[t] = sh2[gc];
  }
  __syncthreads();

  const bf16_t* pr = pp + ((size_t)m * B_ROWS + b) * 16;
  bf16x8 pmv = *(const bf16x8*)pr;
  bf16x8 plv = *(const bf16x8*)(pr + 8);
  f32x4 e0 = *(const f32x4*)(eps + (size_t)b * LT + m * 8);
  f32x4 e1 = *(const f32x4*)(eps + (size_t)b * LT + m * 8 + 4);

  float z[8];
  f32x4 mu0, mu1, lv0, lv1, z0, z1;
#pragma unroll
  for (int l = 0; l < 8; ++l) {
    float muv = (float)pmv[l] * lsc[l] + lsh[l];
    float lvv = (float)plv[l] * lsc[8 + l] + lsh[8 + l];
    float ee  = (l < 4) ? e0[l] : e1[l - 4];
    float zz  = fmaf(expf(lvv * 0.5f), ee, muv);
    z[l] = zz;
    if (l < 4) { mu0[l] = muv; lv0[l] = lvv; z0[l] = zz; }
    else       { mu1[l-4] = muv; lv1[l-4] = lvv; z1[l-4] = zz; }
  }
  {
    const size_t o = (size_t)b * LT + m * 8;
    *(f32x4*)(o_z  + o) = z0; *(f32x4*)(o_z  + o + 4) = z1;
    *(f32x4*)(o_mu + o) = mu0; *(f32x4*)(o_mu + o + 4) = mu1;
    *(f32x4*)(o_lv + o) = lv0; *(f32x4*)(o_lv + o + 4) = lv1;
  }

  float d[32];
#pragma unroll
  for (int j = 0; j < 32; ++j) {
    f32x4 w0 = *(const f32x4*)&wd[j][0];
    f32x4 w1 = *(const f32x4*)&wd[j][4];
    float a = 0.f;
    a = fmaf(w0[0], z[0], a); a = fmaf(w0[1], z[1], a);
    a = fmaf(w0[2], z[2], a); a = fmaf(w0[3], z[3], a);
    a = fmaf(w1[0], z[4], a); a = fmaf(w1[1], z[5], a);
    a = fmaf(w1[2], z[6], a); a = fmaf(w1[3], z[7], a);
    d[j] = a;
  }
  {
    bf16_t* dw = dpre + (size_t)b * H1P + m * 32;
#pragma unroll
    for (int v = 0; v < 4; ++v) {
      bf16x8 o;
#pragma unroll
      for (int j = 0; j < 8; ++j) o[j] = (bf16_t)d[v * 8 + j];
      *(bf16x8*)(dw + v * 8) = o;
    }
  }

  // stats
#pragma unroll
  for (int j = 0; j < 32; ++j) dbuf[t][j] = d[j];
  __syncthreads();
  {
    const int col = t & 31, sl = t >> 5;   // 8 slices of 32 rows
    float s = 0.f, q = 0.f;
#pragma unroll
    for (int r = 0; r < 32; ++r) {
      float v = dbuf[sl * 32 + r][col];
      s += v; q += v * v;
    }
    s += __shfl_xor(s, 32, 64);
    q += __shfl_xor(q, 32, 64);
    const int w = t >> 6;
    if ((t & 63) < 32) { part[0][w][col] = s; part[1][w][col] = q; }
    __syncthreads();
    if (t < 32) {
      float ss = part[0][0][t] + part[0][1][t] + part[0][2][t] + part[0][3][t];
      float qq = part[1][0][t] + part[1][1][t] + part[1][2][t] + part[1][3][t];
      atomicAdd(&sd[m * 32 + t], ss);
      atomicAdd(&qd[m * 32 + t], qq);
    }
  }
}

// ---------------- host ----------------
extern "C" void kernel_launch(void* const* d_in, const int* in_sizes, int n_in,
                              void* d_out, int out_size, void* d_ws, size_t ws_size,
                              hipStream_t stream)
{
  const float* x     = (const float*)d_in[0];
  const float* eps   = (const float*)d_in[1];
  const float* mask1 = (const float*)d_in[2];
  // mask2 (d_in[3]) / maskd (d_in[4]): block-diagonal structure exploited directly
  const float* maskm = (const float*)d_in[5];
  const float* W1    = (const float*)d_in[6];
  // b1 (d_in[7]) cancels in BN (mean subtraction)
  const float* g1    = (const float*)d_in[8];
  const float* be1   = (const float*)d_in[9];
  const float* W2    = (const float*)d_in[10];
  // b2 (d_in[11]) cancels in BN
  const float* g2    = (const float*)d_in[12];
  const float* be2   = (const float*)d_in[13];
  const float* Wd    = (const float*)d_in[14];
  // bd (d_in[15]) cancels in BN
  const float* gd    = (const float*)d_in[16];
  const float* bed   = (const float*)d_in[17];
  const float* Wm    = (const float*)d_in[18];
  float* out = (float*)d_out;
  char*  ws  = (char*)d_ws;

  size_t off = 0;
  auto alloc = [&](size_t bytes) { size_t o = off; off += (bytes + 255) & ~(size_t)255; return o; };
  const size_t XBF  = alloc((size_t)B_ROWS * GENP * 2);   // x bf16; later mo bf16
  const size_t W1M  = alloc((size_t)H1P * GENP * 2);      // W1 masked; later pp
  const size_t WMM  = alloc((size_t)GENP * H1P * 2);      // Wm masked
  const size_t HPRE = alloc((size_t)B_ROWS * H1P * 2);    // h_pre; later d_pre
  const size_t STAT = alloc((size_t)(H1P + H2 + H1P) * 2 * sizeof(float));
  if (ws_size < off) {
    fprintf(stderr, "kernel_launch: workspace too small: need %zu have %zu\n", off, ws_size);
    return;
  }

  bf16_t* xb   = (bf16_t*)(ws + XBF);
  bf16_t* w1m  = (bf16_t*)(ws + W1M);
  bf16_t* wmm  = (bf16_t*)(ws + WMM);
  bf16_t* hpre = (bf16_t*)(ws + HPRE);
  bf16_t* pp   = (bf16_t*)(ws + W1M);   // alias: W1 masked dead after GEMM1 (33.8 MB <= 43.3 MB)
  bf16_t* dpre = (bf16_t*)(ws + HPRE);  // alias: h_pre dead after k_enc2
  bf16_t* mobf = (bf16_t*)(ws + XBF);   // alias: x bf16 dead after GEMM1

  float* s1 = (float*)(ws + STAT);
  float* q1 = s1 + H1P;
  float* s2 = q1 + H1P;
  float* q2 = s2 + H2;
  float* sd = q2 + H2;
  float* qd = sd + H1P;

  float* o_recon = out;
  float* o_z     = o_recon + (size_t)B_ROWS * GEN;
  float* o_mo    = o_z     + (size_t)B_ROWS * LT;
  float* o_mu    = o_mo    + (size_t)B_ROWS * H1;
  float* o_lv    = o_mu    + (size_t)B_ROWS * LT;

  hipMemsetAsync(ws + STAT, 0, (size_t)(H1P + H2 + H1P) * 2 * sizeof(float), stream);

  // prep: cast/mask to bf16, zero-padded (only the two dense weights + x)
  k_prep<<<2048, 256, 0, stream>>>(x,  nullptr, xb,  B_ROWS, GEN, B_ROWS, GENP);
  k_prep<<<2048, 256, 0, stream>>>(W1, mask1,   w1m, H1,  GEN, H1P,  GENP);
  k_prep<<<2048, 256, 0, stream>>>(Wm, maskm,   wmm, GEN, H1,  GENP, H1P);

  // encoder L1: h_pre = x @ W1m^T (+ batch stats)
  gemm_bt<0><<<dim3(H1P / 128, B_ROWS / 128), 256, 0, stream>>>(
      xb, w1m, GENP, hpre, H1P, s1, q1, nullptr, 0);
  k_finalize<<<(H1P + 255) / 256, 256, 0, stream>>>(s1, q1, g1, be1, H1, H1P);

  // encoder L2 (block-diagonal, fused BN1+ELU) -> pp + stats2
  k_enc2<<<dim3(NMOD, B_ROWS / 256), 256, 0, stream>>>(hpre, s1, q1, W2, pp, s2, q2);
  k_finalize<<<(H2 + 255) / 256, 256, 0, stream>>>(s2, q2, g2, be2, H2, H2);

  // decoder L1 (block-diagonal, fused BN2 + reparam) -> dpre + stats_d + z/mu/lv out
  k_dec<<<dim3(NMOD, B_ROWS / 256), 256, 0, stream>>>(pp, s2, q2, eps, Wd,
                                                      o_z, o_mu, o_lv, dpre, sd, qd);
  k_finalize<<<(H1P + 255) / 256, 256, 0, stream>>>(sd, qd, gd, bed, H1, H1P);

  // BN_d + ELU -> module_outputs (bf16 padded + f32 out)
  k_bn_elu<<<2048, 256, 0, stream>>>(dpre, sd, qd, mobf, o_mo, H1, H1P, 1);

  // merger: global_recon = mo @ Wmm^T (f32 out)
  gemm_bt<1><<<dim3(GENP / 128, B_ROWS / 128), 256, 0, stream>>>(
      mobf, wmm, H1P, nullptr, 0, nullptr, nullptr, o_recon, GEN);
}

// Round 7
// 1273.504 us; speedup vs baseline: 1.7974x; 1.0116x over previous
//
#include <hip/hip_runtime.h>
#include <cstdio>
#include <cstdint>

typedef __bf16 bf16_t;
typedef __bf16 bf16x8 __attribute__((ext_vector_type(8)));
typedef __bf16 bf16x4 __attribute__((ext_vector_type(4)));
typedef float  f32x4  __attribute__((ext_vector_type(4)));

// problem dims
#define B_ROWS 8192
#define GEN    5000
#define GENP   5120   // padded K for gemm1 / N for merger (mult of 256, 64)
#define H1     4128
#define H1P    4224   // mult of 128 and 64; gemm1 N split as 4096 (256^2) + 128 (tail)
#define H2     2064
#define LT     1032
#define NMOD   129    // pathway modules (incl. aux)

// ---------------- async global->LDS helper ----------------
__device__ __forceinline__ void load_lds16(const bf16_t* g, bf16_t* l) {
  __builtin_amdgcn_global_load_lds((__attribute__((address_space(1))) void*)g,
                                   (__attribute__((address_space(3))) void*)l,
                                   16, 0, 0);
}

__device__ __forceinline__ int xcd_swizzle(int wg, int nwg) {
  const int q = nwg >> 3, r8 = nwg & 7;
  const int xcd = wg & 7, sidx = wg >> 3;
  return (xcd < r8 ? xcd * (q + 1) : r8 * (q + 1) + (xcd - r8) * q) + sidx;
}

// =======================================================================
// 256x256 8-wave 8-phase GEMM, deep counted-vmcnt ledger (T2+T3+T4+T5).
// BK=64, 2 K-tiles/iter (T->buf0, T+1->buf1). 16 loads/iter, ~2/phase:
//   prevP8: A[T+1]g0,g2      P1: A[T+1]g1,g3    P3/P4: B[T+2] (2+2)
//   P5/P6:  A[T+2] (2+2)     P7:  B[T+3]g0,g1   P8: B[T+3]g2,g3 + A[T+3]g0,g2
// Waits: vmcnt(4) @P4 (completes A[T+1], issued 4-7 phases earlier; leaves
// P3/P4's B[T+2]); vmcnt(6) @P8 (completes A[T+2],B[T+2]; leaves P7+P8's 6).
// Buffer-free proof: A-buf1 overwrite (prevP8/P1) after A[T-1] last read
// prevP7; B-buf0 (P3/P4) after B[T] last read P2; A-buf0 (P5/P6) after A[T]
// last read P3; B-buf1 (P7/P8) after B[T+1] last read P6; A-buf1 A[T+3] (P8)
// after A[T+1] last read P7. Reads complete before each wave's phase-closing
// barrier (lgkmcnt(0) precedes MFMA precedes barrier) -> no overwrite race.
// pf3 == pf2 for even NT stepping by 2 (pf3 false only in last iter).
// MODE 0: bf16 C (ld Npad) + per-column sum/sumsq atomics.
// MODE 1: f32 C (ld Nvalid, col-bounded).
// =======================================================================
template<int MODE>
__global__ __launch_bounds__(512, 2)
void gemm256(const bf16_t* __restrict__ A, const bf16_t* __restrict__ Bm,
             int K, bf16_t* __restrict__ Cb, int Npad,
             float* __restrict__ sum, float* __restrict__ sq,
             float* __restrict__ Cf, int Nvalid)
{
  __shared__ bf16_t As[2][256 * 64];
  __shared__ bf16_t Bs[2][256 * 64];
  const int tid  = threadIdx.x;
  const int wave = tid >> 6;
  const int lane = tid & 63;

  int wg = xcd_swizzle((int)blockIdx.x + (int)blockIdx.y * gridDim.x,
                       gridDim.x * gridDim.y);
  const int brow = (wg / gridDim.x) * 256;
  const int bcol = (wg % gridDim.x) * 256;

  const int wm = wave >> 2;      // 0..1 -> 128-row half
  const int wn = wave & 3;       // 0..3 -> 64-col slice

  // staging: 8 threads per 64-elem row, 16B granule, XOR-swizzled source
  const int rr = tid >> 3;                        // 0..63
  const int cc = (((tid & 7) ^ (rr & 7)) << 3);
  const bf16_t* ga = A  + (size_t)(brow + rr) * K + cc;
  const bf16_t* gb = Bm + (size_t)(bcol + rr) * K + cc;

  auto stA = [&](int d, int i, long ko) {
    load_lds16(ga + (size_t)(i * 64) * K + ko, &As[d][(i * 64 + wave * 8) * 64]);
  };
  auto stB = [&](int d, int i, long ko) {
    load_lds16(gb + (size_t)(i * 64) * K + ko, &Bs[d][(i * 64 + wave * 8) * 64]);
  };

  f32x4 acc[8][4] = {};
  bf16x8 alo[4][2], ahi[4][2], blo[2][2], bhi[2][2];

  const int lr  = lane & 15;
  const int hi  = lane >> 4;
  const int rsw = lr & 7;
  const int arb = wm * 128 + lr;  // A row base (+ MB*64 + mf*16)
  const int bcb = wn * 64 + lr;   // B col base (+ nf*16)

#define RD_A(DST, MB, dd)                                                     \
  _Pragma("unroll") for (int mf = 0; mf < 4; ++mf)                            \
  _Pragma("unroll") for (int kk = 0; kk < 2; ++kk)                            \
    DST[mf][kk] = *(const bf16x8*)&As[dd][(arb + (MB) * 64 + mf * 16) * 64 +  \
                                          (((kk * 4 + hi) ^ rsw) << 3)];
#define RD_B(DST, NB, dd)                                                     \
  _Pragma("unroll") for (int nf = 0; nf < 2; ++nf)                            \
  _Pragma("unroll") for (int kk = 0; kk < 2; ++kk)                            \
    DST[nf][kk] = *(const bf16x8*)&Bs[dd][(bcb + (NB) * 16 + nf * 16) * 64 +  \
                                          (((kk * 4 + hi) ^ rsw) << 3)];
#define MFMA_Q(AF, BF, MB, NB)                                                \
  _Pragma("unroll") for (int mf = 0; mf < 4; ++mf)                            \
  _Pragma("unroll") for (int nf = 0; nf < 2; ++nf)                            \
  _Pragma("unroll") for (int kk = 0; kk < 2; ++kk)                            \
    acc[(MB) + mf][(NB) + nf] = __builtin_amdgcn_mfma_f32_16x16x32_bf16(      \
        AF[mf][kk], BF[nf][kk], acc[(MB) + mf][(NB) + nf], 0, 0, 0);

#define LGKM0  asm volatile("s_waitcnt lgkmcnt(0)" ::: "memory")
#define LGKM8  asm volatile("s_waitcnt lgkmcnt(8)" ::: "memory")
#define VMW(N) asm volatile("s_waitcnt vmcnt(" #N ")" ::: "memory")
#define BARR   __builtin_amdgcn_s_barrier()
#define PRIO1  __builtin_amdgcn_s_setprio(1)
#define PRIO0  __builtin_amdgcn_s_setprio(0)

  const int NT = K >> 6;          // even by construction

  // prologue: A[0],B[0]->buf0 (complete); B[1]->buf1 + A[1]g0,g2->buf1 in flight
  stA(0, 0, 0); stA(0, 1, 0); stA(0, 2, 0); stA(0, 3, 0);
  stB(0, 0, 0); stB(0, 1, 0); stB(0, 2, 0); stB(0, 3, 0);
  stB(1, 0, 64); stB(1, 1, 64); stB(1, 2, 64); stB(1, 3, 64);
  stA(1, 0, 64); stA(1, 2, 64);
  VMW(6);                        // completes A[0],B[0]; leaves B[1](4)+A[1](2)
  BARR;

  for (int it = 0; it < (NT >> 1); ++it) {
    const int  T   = it * 2;
    const long k1  = (long)(T + 1) * 64;
    const long k2  = (long)(T + 2) * 64;
    const long k3  = (long)(T + 3) * 64;
    const bool pf2 = (T + 2 < NT);   // implies T+3 < NT too (NT even)

    // P1: Q(lo,lo) of T; stage A[T+1]g1,g3 -> buf1
    RD_A(alo, 0, 0); RD_B(blo, 0, 0);
    stA(1, 1, k1); stA(1, 3, k1);
    LGKM8;
    BARR; LGKM0; PRIO1; MFMA_Q(alo, blo, 0, 0); PRIO0; BARR;

    // P2: Q(lo,hi)
    RD_B(bhi, 2, 0);
    BARR; LGKM0; PRIO1; MFMA_Q(alo, bhi, 0, 2); PRIO0; BARR;

    // P3: Q(hi,hi); stage B[T+2]g0,g1 -> buf0 (B[T] reads retired @P2)
    RD_A(ahi, 1, 0);
    if (pf2) { stB(0, 0, k2); stB(0, 1, k2); }
    BARR; LGKM0; PRIO1; MFMA_Q(ahi, bhi, 4, 2); PRIO0; BARR;

    // P4: Q(hi,lo); stage B[T+2]g2,g3; counted wait -> A[T+1] ready
    if (pf2) { stB(0, 2, k2); stB(0, 3, k2); }
    PRIO1; MFMA_Q(ahi, blo, 4, 0); PRIO0;
    if (pf2) { VMW(4); } else { VMW(0); }
    BARR;

    // P5: Q(lo,lo) of T+1; stage A[T+2]g0,g2 -> buf0 (A[T] retired @P3)
    RD_A(alo, 0, 1); RD_B(blo, 0, 1);
    if (pf2) { stA(0, 0, k2); stA(0, 2, k2); }
    LGKM8;
    BARR; LGKM0; PRIO1; MFMA_Q(alo, blo, 0, 0); PRIO0; BARR;

    // P6: Q(lo,hi); stage A[T+2]g1,g3
    RD_B(bhi, 2, 1);
    if (pf2) { stA(0, 1, k2); stA(0, 3, k2); }
    BARR; LGKM0; PRIO1; MFMA_Q(alo, bhi, 0, 2); PRIO0; BARR;

    // P7: Q(hi,hi); stage B[T+3]g0,g1 -> buf1 (B[T+1] retired @P6)
    RD_A(ahi, 1, 1);
    if (pf2) { stB(1, 0, k3); stB(1, 1, k3); }
    BARR; LGKM0; PRIO1; MFMA_Q(ahi, bhi, 4, 2); PRIO0; BARR;

    // P8: Q(hi,lo); stage B[T+3]g2,g3 + A[T+3]g0,g2 (A[T+1] retired @P7)
    if (pf2) { stB(1, 2, k3); stB(1, 3, k3); stA(1, 0, k3); stA(1, 2, k3); }
    PRIO1; MFMA_Q(ahi, blo, 4, 0); PRIO0;
    if (pf2) { VMW(6); BARR; }       // completes A[T+2],B[T+2]; leaves P7+P8's 6
  }

  // epilogue: C/D layout col=lane&15, row=(lane>>4)*4+reg
  if (MODE == 0) {
#pragma unroll
    for (int nf = 0; nf < 4; ++nf) {
      const int colg = bcol + wn * 64 + nf * 16 + lr;
      float s = 0.f, s2 = 0.f;
#pragma unroll
      for (int mf = 0; mf < 8; ++mf) {
        const int rowg = brow + wm * 128 + mf * 16 + hi * 4;
#pragma unroll
        for (int r = 0; r < 4; ++r) {
          float v = acc[mf][nf][r];
          s += v; s2 += v * v;
          Cb[(size_t)(rowg + r) * Npad + colg] = (bf16_t)v;
        }
      }
      s  += __shfl_xor(s, 16, 64);  s  += __shfl_xor(s, 32, 64);
      s2 += __shfl_xor(s2, 16, 64); s2 += __shfl_xor(s2, 32, 64);
      if (lane < 16) {
        atomicAdd(&sum[colg], s);
        atomicAdd(&sq[colg], s2);
      }
    }
  } else {
#pragma unroll
    for (int nf = 0; nf < 4; ++nf) {
      const int colg = bcol + wn * 64 + nf * 16 + lr;
      if (colg < Nvalid) {
#pragma unroll
        for (int mf = 0; mf < 8; ++mf) {
          const int rowg = brow + wm * 128 + mf * 16 + hi * 4;
#pragma unroll
          for (int r = 0; r < 4; ++r)
            Cf[(size_t)(rowg + r) * Nvalid + colg] = acc[mf][nf][r];
        }
      }
    }
  }
#undef RD_A
#undef RD_B
#undef MFMA_Q
#undef LGKM0
#undef LGKM8
#undef VMW
#undef BARR
#undef PRIO1
#undef PRIO0
}

// =======================================================================
// 128x128 4-wave GEMM (round-2 structure) — tail strip
// =======================================================================
template<int MODE>
__global__ __launch_bounds__(256, 2)
void gemm_bt(const bf16_t* __restrict__ A, const bf16_t* __restrict__ Bm,
             int K, bf16_t* __restrict__ Cb, int Npad,
             float* __restrict__ sum, float* __restrict__ sq,
             float* __restrict__ Cf, int Nvalid)
{
  __shared__ bf16_t As[128 * 64];
  __shared__ bf16_t Bs[128 * 64];
  const int tid  = threadIdx.x;
  const int wave = tid >> 6;
  const int lane = tid & 63;

  int wg = xcd_swizzle((int)blockIdx.x + (int)blockIdx.y * gridDim.x,
                       gridDim.x * gridDim.y);
  const int brow = (wg / gridDim.x) * 128;
  const int bcol = (wg % gridDim.x) * 128;

  const int wrow = (wave >> 1) * 64;
  const int wcol = (wave & 1) * 64;

  const int rr  = tid >> 3;                         // 0..31
  const int cc  = (((tid & 7) ^ (rr & 7)) << 3);    // swizzled 8-elem granule

  const bf16_t* ga[4];
  const bf16_t* gb[4];
#pragma unroll
  for (int i = 0; i < 4; ++i) {
    ga[i] = A  + (size_t)(brow + i * 32 + rr) * K + cc;
    gb[i] = Bm + (size_t)(bcol + i * 32 + rr) * K + cc;
  }
  bf16_t* lab = As + wave * 512;
  bf16_t* lbb = Bs + wave * 512;

  f32x4 acc[4][4] = {};

  const int lr  = lane & 15;
  const int g0  = lane >> 4;
  const int rsw = lr & 7;

  for (int kt = 0; kt < K; kt += 64) {
#pragma unroll
    for (int i = 0; i < 4; ++i) {
      load_lds16(ga[i] + kt, lab + i * 2048);
      load_lds16(gb[i] + kt, lbb + i * 2048);
    }
    __syncthreads();
#pragma unroll
    for (int kk = 0; kk < 2; ++kk) {
      const int swz = (((kk * 4 + g0) ^ rsw) << 3);
      bf16x8 af[4], bfr[4];
#pragma unroll
      for (int mi = 0; mi < 4; ++mi)
        af[mi] = *(const bf16x8*)(As + (wrow + mi * 16 + lr) * 64 + swz);
#pragma unroll
      for (int ni = 0; ni < 4; ++ni)
        bfr[ni] = *(const bf16x8*)(Bs + (wcol + ni * 16 + lr) * 64 + swz);
#pragma unroll
      for (int mi = 0; mi < 4; ++mi)
#pragma unroll
        for (int ni = 0; ni < 4; ++ni)
          acc[mi][ni] = __builtin_amdgcn_mfma_f32_16x16x32_bf16(af[mi], bfr[ni], acc[mi][ni], 0, 0, 0);
    }
    __syncthreads();
  }

  const int lcol = lane & 15;
  const int lrow = (lane >> 4) * 4;
  if (MODE == 0) {
#pragma unroll
    for (int ni = 0; ni < 4; ++ni) {
      const int colg = bcol + wcol + ni * 16 + lcol;
      float s = 0.f, s2 = 0.f;
#pragma unroll
      for (int mi = 0; mi < 4; ++mi) {
        const int rowg = brow + wrow + mi * 16 + lrow;
#pragma unroll
        for (int r = 0; r < 4; ++r) {
          float v = acc[mi][ni][r];
          s += v; s2 += v * v;
          Cb[(size_t)(rowg + r) * Npad + colg] = (bf16_t)v;
        }
      }
      s  += __shfl_xor(s, 16, 64);  s  += __shfl_xor(s, 32, 64);
      s2 += __shfl_xor(s2, 16, 64); s2 += __shfl_xor(s2, 32, 64);
      if (lane < 16) {
        atomicAdd(&sum[colg], s);
        atomicAdd(&sq[colg], s2);
      }
    }
  } else {
#pragma unroll
    for (int ni = 0; ni < 4; ++ni) {
      const int colg = bcol + wcol + ni * 16 + lcol;
      if (colg < Nvalid) {
#pragma unroll
        for (int mi = 0; mi < 4; ++mi) {
          const int rowg = brow + wrow + mi * 16 + lrow;
#pragma unroll
          for (int r = 0; r < 4; ++r)
            Cf[(size_t)(rowg + r) * Nvalid + colg] = acc[mi][ni][r];
        }
      }
    }
  }
}

// ---------------- prep: out[npad][kpad] = bf16(W*mask), zero-padded ----------------
__global__ void k_prep(const float* __restrict__ W, const float* __restrict__ Mk,
                       bf16_t* __restrict__ out, int N, int K, int Npad, int Kpad)
{
  const int  kg    = Kpad >> 3;
  const long total = (long)Npad * kg;
  for (long idx = (long)blockIdx.x * blockDim.x + threadIdx.x; idx < total;
       idx += (long)gridDim.x * blockDim.x) {
    const int n = (int)(idx / kg);
    const int c = (int)(idx % kg) * 8;
    bf16x8 o;
#pragma unroll
    for (int j = 0; j < 8; ++j) o[j] = (bf16_t)0.f;
    if (n < N && c < K) {               // K % 8 == 0 for all inputs
      const f32x4* w4 = (const f32x4*)(W + (size_t)n * K + c);
      f32x4 a = w4[0], b = w4[1];
      if (Mk) {
        const f32x4* m4 = (const f32x4*)(Mk + (size_t)n * K + c);
        f32x4 ma = m4[0], mb = m4[1];
        a *= ma; b *= mb;
      }
#pragma unroll
      for (int j = 0; j < 4; ++j) { o[j] = (bf16_t)a[j]; o[4 + j] = (bf16_t)b[j]; }
    }
    *(bf16x8*)(out + (size_t)idx * 8) = o;
  }
}

// ---------------- BN finalize: sum->scale, sq->shift ----------------
__global__ void k_finalize(float* __restrict__ sum, float* __restrict__ sq,
                           const float* __restrict__ g, const float* __restrict__ be,
                           int Nvalid, int Npad)
{
  const int c = blockIdx.x * blockDim.x + threadIdx.x;
  if (c >= Npad) return;
  float sc = 0.f, sh = 0.f;
  if (c < Nvalid) {
    const float invM = 1.0f / 8192.0f;
    float mean = sum[c] * invM;
    float var  = sq[c] * invM - mean * mean;
    sc = g[c] * rsqrtf(var + 1e-3f);
    sh = be[c] - mean * sc;
  }
  sum[c] = sc; sq[c] = sh;
}

// ---------------- BN apply (+optional ELU, optional f32 out) ----------------
__global__ void k_bn_elu(const bf16_t* __restrict__ pre, const float* __restrict__ sc,
                         const float* __restrict__ sh, bf16_t* __restrict__ outb,
                         float* __restrict__ outf, int Nvalid, int Npad, int elu)
{
  const int  ng    = Npad >> 3;
  const long total = (long)B_ROWS * ng;
  for (long idx = (long)blockIdx.x * blockDim.x + threadIdx.x; idx < total;
       idx += (long)gridDim.x * blockDim.x) {
    const int r = (int)(idx / ng);
    const int c = (int)(idx % ng) * 8;
    bf16x8 o;
#pragma unroll
    for (int j = 0; j < 8; ++j) o[j] = (bf16_t)0.f;
    if (c < Nvalid) {                   // Nvalid % 8 == 0 -> group fully valid
      bf16x8 x = *(const bf16x8*)(pre + (size_t)r * Npad + c);
      f32x4 y0, y1;
#pragma unroll
      for (int j = 0; j < 8; ++j) {
        float v = (float)x[j] * sc[c + j] + sh[c + j];
        if (elu) v = v > 0.f ? v : expm1f(v);
        if (j < 4) y0[j] = v; else y1[j - 4] = v;
        o[j] = (bf16_t)v;
      }
      if (outf) {
        float* p = outf + (size_t)r * Nvalid + c;
        *(f32x4*)p       = y0;
        *(f32x4*)(p + 4) = y1;
      }
    }
    *(bf16x8*)(outb + (size_t)r * Npad + c) = o;
  }
}

// =======================================================================
// k_enc2: block-diagonal encoder L2, fused BN1+ELU (round-6, verified)
// =======================================================================
__global__ __launch_bounds__(256)
void k_enc2(const bf16_t* __restrict__ hpre,
            const float* __restrict__ sc1, const float* __restrict__ sh1,
            const float* __restrict__ W2,
            bf16_t* __restrict__ pp,
            float* __restrict__ s2, float* __restrict__ q2)
{
  __shared__ float ws2[16][32];
  __shared__ float lsc[32], lsh[32];
  __shared__ float dbuf[256][17];
  __shared__ float part[2][4][16];
  const int m = blockIdx.x;
  const int t = threadIdx.x;
  const int b = blockIdx.y * 256 + t;

  for (int i = t; i < 512; i += 256) {
    const int r = i >> 5, j = i & 31;
    const int grow = (r < 8) ? (m * 8 + r) : (LT + m * 8 + (r - 8));
    ws2[r][j] = W2[(size_t)grow * H1 + m * 32 + j];
  }
  if (t < 32) lsc[t] = sc1[m * 32 + t];
  else if (t < 64) lsh[t - 32] = sh1[m * 32 + (t - 32)];
  __syncthreads();

  float h[32];
  const bf16_t* hp = hpre + (size_t)b * H1P + m * 32;
#pragma unroll
  for (int v = 0; v < 4; ++v) {
    bf16x8 x = *(const bf16x8*)(hp + v * 8);
#pragma unroll
    for (int j = 0; j < 8; ++j) {
      float val = (float)x[j] * lsc[v * 8 + j] + lsh[v * 8 + j];
      h[v * 8 + j] = val > 0.f ? val : expm1f(val);
    }
  }

  float p[16];
#pragma unroll
  for (int i = 0; i < 16; ++i) {
    float a = 0.f;
#pragma unroll
    for (int jb = 0; jb < 8; ++jb) {
      f32x4 w = *(const f32x4*)&ws2[i][jb * 4];
      a = fmaf(w[0], h[jb * 4 + 0], a);
      a = fmaf(w[1], h[jb * 4 + 1], a);
      a = fmaf(w[2], h[jb * 4 + 2], a);
      a = fmaf(w[3], h[jb * 4 + 3], a);
    }
    p[i] = a;
  }

  bf16x8 o0, o1;
#pragma unroll
  for (int i = 0; i < 8; ++i) { o0[i] = (bf16_t)p[i]; o1[i] = (bf16_t)p[8 + i]; }
  bf16_t* pw = pp + ((size_t)m * B_ROWS + b) * 16;
  *(bf16x8*)pw = o0; *(bf16x8*)(pw + 8) = o1;

  // stats
#pragma unroll
  for (int i = 0; i < 16; ++i) dbuf[t][i] = p[i];
  __syncthreads();
  {
    const int col = t & 15, sl = t >> 4;   // 16 slices of 16 rows
    float s = 0.f, q = 0.f;
#pragma unroll
    for (int r = 0; r < 16; ++r) {
      float v = dbuf[sl * 16 + r][col];
      s += v; q += v * v;
    }
    s += __shfl_xor(s, 16, 64); s += __shfl_xor(s, 32, 64);
    q += __shfl_xor(q, 16, 64); q += __shfl_xor(q, 32, 64);
    const int w = t >> 6;
    if ((t & 63) < 16) { part[0][w][col] = s; part[1][w][col] = q; }
    __syncthreads();
    if (t < 16) {
      float ss = part[0][0][t] + part[0][1][t] + part[0][2][t] + part[0][3][t];
      float qq = part[1][0][t] + part[1][1][t] + part[1][2][t] + part[1][3][t];
      const int gc = (t < 8) ? (m * 8 + t) : (LT + m * 8 + (t - 8));
      atomicAdd(&s2[gc], ss);
      atomicAdd(&q2[gc], qq);
    }
  }
}

// =======================================================================
// k_dec: fused BN2 + reparametrize + block-diagonal decoder L1 (round-6)
// =======================================================================
__global__ __launch_bounds__(256)
void k_dec(const bf16_t* __restrict__ pp,
           const float* __restrict__ sc2, const float* __restrict__ sh2,
           const float* __restrict__ eps, const float* __restrict__ Wd,
           float* __restrict__ o_z, float* __restrict__ o_mu, float* __restrict__ o_lv,
           bf16_t* __restrict__ dpre,
           float* __restrict__ sd, float* __restrict__ qd)
{
  __shared__ float wd[32][8];
  __shared__ float lsc[16], lsh[16];
  __shared__ float dbuf[256][33];
  __shared__ float part[2][4][32];
  const int m = blockIdx.x;
  const int t = threadIdx.x;
  const int b = blockIdx.y * 256 + t;

  {
    const int j = t >> 3, l = t & 7;
    wd[j][l] = Wd[(size_t)(m * 32 + j) * LT + m * 8 + l];
  }
  if (t < 16) {
    const int gc = (t < 8) ? (m * 8 + t) : (LT + m * 8 + (t - 8));
    lsc[t] = sc2[gc]; lsh[t] = sh2[gc];
  }
  __syncthreads();

  const bf16_t* pr = pp + ((size_t)m * B_ROWS + b) * 16;
  bf16x8 pmv = *(const bf16x8*)pr;
  bf16x8 plv = *(const bf16x8*)(pr + 8);
  f32x4 e0 = *(const f32x4*)(eps + (size_t)b * LT + m * 8);
  f32x4 e1 = *(const f32x4*)(eps + (size_t)b * LT + m * 8 + 4);

  float z[8];
  f32x4 mu0, mu1, lv0, lv1, z0, z1;
#pragma unroll
  for (int l = 0; l < 8; ++l) {
    float muv = (float)pmv[l] * lsc[l] + lsh[l];
    float lvv = (float)plv[l] * lsc[8 + l] + lsh[8 + l];
    float ee  = (l < 4) ? e0[l] : e1[l - 4];
    float zz  = fmaf(expf(lvv * 0.5f), ee, muv);
    z[l] = zz;
    if (l < 4) { mu0[l] = muv; lv0[l] = lvv; z0[l] = zz; }
    else       { mu1[l-4] = muv; lv1[l-4] = lvv; z1[l-4] = zz; }
  }
  {
    const size_t o = (size_t)b * LT + m * 8;
    *(f32x4*)(o_z  + o) = z0; *(f32x4*)(o_z  + o + 4) = z1;
    *(f32x4*)(o_mu + o) = mu0; *(f32x4*)(o_mu + o + 4) = mu1;
    *(f32x4*)(o_lv + o) = lv0; *(f32x4*)(o_lv + o + 4) = lv1;
  }

  float d[32];
#pragma unroll
  for (int j = 0; j < 32; ++j) {
    f32x4 w0 = *(const f32x4*)&wd[j][0];
    f32x4 w1 = *(const f32x4*)&wd[j][4];
    float a = 0.f;
    a = fmaf(w0[0], z[0], a); a = fmaf(w0[1], z[1], a);
    a = fmaf(w0[2], z[2], a); a = fmaf(w0[3], z[3], a);
    a = fmaf(w1[0], z[4], a); a = fmaf(w1[1], z[5], a);
    a = fmaf(w1[2], z[6], a); a = fmaf(w1[3], z[7], a);
    d[j] = a;
  }
  {
    bf16_t* dw = dpre + (size_t)b * H1P + m * 32;
#pragma unroll
    for (int v = 0; v < 4; ++v) {
      bf16x8 o;
#pragma unroll
      for (int j = 0; j < 8; ++j) o[j] = (bf16_t)d[v * 8 + j];
      *(bf16x8*)(dw + v * 8) = o;
    }
  }

  // stats
#pragma unroll
  for (int j = 0; j < 32; ++j) dbuf[t][j] = d[j];
  __syncthreads();
  {
    const int col = t & 31, sl = t >> 5;   // 8 slices of 32 rows
    float s = 0.f, q = 0.f;
#pragma unroll
    for (int r = 0; r < 32; ++r) {
      float v = dbuf[sl * 32 + r][col];
      s += v; q += v * v;
    }
    s += __shfl_xor(s, 32, 64);
    q += __shfl_xor(q, 32, 64);
    const int w = t >> 6;
    if ((t & 63) < 32) { part[0][w][col] = s; part[1][w][col] = q; }
    __syncthreads();
    if (t < 32) {
      float ss = part[0][0][t] + part[0][1][t] + part[0][2][t] + part[0][3][t];
      float qq = part[1][0][t] + part[1][1][t] + part[1][2][t] + part[1][3][t];
      atomicAdd(&sd[m * 32 + t], ss);
      atomicAdd(&qd[m * 32 + t], qq);
    }
  }
}

// ---------------- host ----------------
extern "C" void kernel_launch(void* const* d_in, const int* in_sizes, int n_in,
                              void* d_out, int out_size, void* d_ws, size_t ws_size,
                              hipStream_t stream)
{
  const float* x     = (const float*)d_in[0];
  const float* eps   = (const float*)d_in[1];
  const float* mask1 = (const float*)d_in[2];
  // mask2 (d_in[3]) / maskd (d_in[4]): block-diagonal structure exploited directly
  const float* maskm = (const float*)d_in[5];
  const float* W1    = (const float*)d_in[6];
  // b1 (d_in[7]) cancels in BN (mean subtraction)
  const float* g1    = (const float*)d_in[8];
  const float* be1   = (const float*)d_in[9];
  const float* W2    = (const float*)d_in[10];
  // b2 (d_in[11]) cancels in BN
  const float* g2    = (const float*)d_in[12];
  const float* be2   = (const float*)d_in[13];
  const float* Wd    = (const float*)d_in[14];
  // bd (d_in[15]) cancels in BN
  const float* gd    = (const float*)d_in[16];
  const float* bed   = (const float*)d_in[17];
  const float* Wm    = (const float*)d_in[18];
  float* out = (float*)d_out;
  char*  ws  = (char*)d_ws;

  size_t off = 0;
  auto alloc = [&](size_t bytes) { size_t o = off; off += (bytes + 255) & ~(size_t)255; return o; };
  const size_t XBF  = alloc((size_t)B_ROWS * GENP * 2);   // x bf16; later mo bf16
  const size_t W1M  = alloc((size_t)H1P * GENP * 2);      // W1 masked; later pp
  const size_t WMM  = alloc((size_t)GENP * H1P * 2);      // Wm masked
  const size_t HPRE = alloc((size_t)B_ROWS * H1P * 2);    // h_pre; later d_pre
  const size_t STAT = alloc((size_t)(H1P + H2 + H1P) * 2 * sizeof(float));
  if (ws_size < off) {
    fprintf(stderr, "kernel_launch: workspace too small: need %zu have %zu\n", off, ws_size);
    return;
  }

  bf16_t* xb   = (bf16_t*)(ws + XBF);
  bf16_t* w1m  = (bf16_t*)(ws + W1M);
  bf16_t* wmm  = (bf16_t*)(ws + WMM);
  bf16_t* hpre = (bf16_t*)(ws + HPRE);
  bf16_t* pp   = (bf16_t*)(ws + W1M);   // alias: W1 masked dead after GEMM1
  bf16_t* dpre = (bf16_t*)(ws + HPRE);  // alias: h_pre dead after k_enc2
  bf16_t* mobf = (bf16_t*)(ws + XBF);   // alias: x bf16 dead after GEMM1

  float* s1 = (float*)(ws + STAT);
  float* q1 = s1 + H1P;
  float* s2 = q1 + H1P;
  float* q2 = s2 + H2;
  float* sd = q2 + H2;
  float* qd = sd + H1P;

  float* o_recon = out;
  float* o_z     = o_recon + (size_t)B_ROWS * GEN;
  float* o_mo    = o_z     + (size_t)B_ROWS * LT;
  float* o_mu    = o_mo    + (size_t)B_ROWS * H1;
  float* o_lv    = o_mu    + (size_t)B_ROWS * LT;

  hipMemsetAsync(ws + STAT, 0, (size_t)(H1P + H2 + H1P) * 2 * sizeof(float), stream);

  // prep: cast/mask to bf16, zero-padded
  k_prep<<<2048, 256, 0, stream>>>(x,  nullptr, xb,  B_ROWS, GEN, B_ROWS, GENP);
  k_prep<<<2048, 256, 0, stream>>>(W1, mask1,   w1m, H1,  GEN, H1P,  GENP);
  k_prep<<<2048, 256, 0, stream>>>(Wm, maskm,   wmm, GEN, H1,  GENP, H1P);

  // encoder L1: h_pre = x @ W1m^T (+ batch stats)
  // main: cols 0..4095 via 256^2 8-phase (512 blocks = 2 full CU generations)
  gemm256<0><<<dim3(4096 / 256, B_ROWS / 256), 512, 0, stream>>>(
      xb, w1m, GENP, hpre, H1P, s1, q1, nullptr, 0);
  // tail: cols 4096..4223 via 128^2 (pointer offsets into B / C / stats)
  gemm_bt<0><<<dim3(1, B_ROWS / 128), 256, 0, stream>>>(
      xb, w1m + (size_t)4096 * GENP, GENP, hpre + 4096, H1P,
      s1 + 4096, q1 + 4096, nullptr, 0);
  k_finalize<<<(H1P + 255) / 256, 256, 0, stream>>>(s1, q1, g1, be1, H1, H1P);

  // encoder L2 (block-diagonal, fused BN1+ELU) -> pp + stats2
  k_enc2<<<dim3(NMOD, B_ROWS / 256), 256, 0, stream>>>(hpre, s1, q1, W2, pp, s2, q2);
  k_finalize<<<(H2 + 255) / 256, 256, 0, stream>>>(s2, q2, g2, be2, H2, H2);

  // decoder L1 (block-diagonal, fused BN2 + reparam) -> dpre + stats_d + z/mu/lv
  k_dec<<<dim3(NMOD, B_ROWS / 256), 256, 0, stream>>>(pp, s2, q2, eps, Wd,
                                                      o_z, o_mu, o_lv, dpre, sd, qd);
  k_finalize<<<(H1P + 255) / 256, 256, 0, stream>>>(sd, qd, gd, bed, H1, H1P);

  // BN_d + ELU -> module_outputs (bf16 padded + f32 out)
  k_bn_elu<<<2048, 256, 0, stream>>>(dpre, sd, qd, mobf, o_mo, H1, H1P, 1);

  // merger: global_recon = mo @ Wmm^T (f32 out)  [256^2 8-phase, 640 blocks]
  gemm256<1><<<dim3(GENP / 256, B_ROWS / 256), 512, 0, stream>>>(
      mobf, wmm, H1P, nullptr, 0, nullptr, nullptr, o_recon, GEN);
}